// Round 3
// baseline (382.498 us; speedup 1.0000x reference)
//
#include <hip/hip_runtime.h>

typedef unsigned short u16;
typedef unsigned int u32;
typedef __attribute__((ext_vector_type(8))) short short8;   // 8 x bf16
typedef __attribute__((ext_vector_type(4))) float f32x4;

// ---------------- workspace layout (bytes) ----------------
#define OFF_WM    0         // float[801]: wmean[0..799] (pad 0), [800]=mean(b_in)
#define OFF_WINF  3584      // u16 [25][8][64][8]  W_in B-fragment-linear   (204800 B)
#define OFF_WEGF  208384    // u16 [6][17][64][8]  experts+gate frag-linear (104448 B)
#define OFF_WCTXF 312832    // u16 [2][8][64][8]   W_ctx frag-linear        (16384 B)
#define OFF_WOUTF 329216    // u16 [4][64][8]      W_out frag-linear        (4096 B)

__device__ __forceinline__ u16 f2bf(float x) {
  union { float f; u32 u; } v; v.f = x;
  u32 r = v.u + 0x7FFFu + ((v.u >> 16) & 1u);   // RNE
  return (u16)(r >> 16);
}

// ------------------------------------------------------------------
// Prep: wmean for the exact fp32 t path; all weights -> bf16 in
// MFMA-B-fragment-linear order: frag[tile][lane][j] with
// k = kt*32 + (lane>>4)*8 + j, n = ct*16 + (lane&15).
// ------------------------------------------------------------------
__global__ void prep_kernel(const float* __restrict__ W_in, const float* __restrict__ b_in,
                            const float* __restrict__ W_gate, const float* __restrict__ W_exp,
                            const float* __restrict__ W_ctx, const float* __restrict__ W_out,
                            float* __restrict__ wm, u16* __restrict__ WinF,
                            u16* __restrict__ WegF, u16* __restrict__ WctxF,
                            u16* __restrict__ WoutF) {
  int idx = blockIdx.x * 256 + threadIdx.x;
  if (idx < 801) {
    if (idx == 800) {
      float s = 0.f;
      for (int j = 0; j < 128; ++j) s += b_in[j];
      wm[800] = s * (1.f / 128.f);
    } else if (idx >= 784) {
      wm[idx] = 0.f;
    } else {
      float s = 0.f;
      for (int j = 0; j < 128; ++j) s += W_in[idx * 128 + j];
      wm[idx] = s * (1.f / 128.f);
    }
  } else if (idx < 103201) {                    // WinF: 25*8 tiles
    int f = idx - 801;
    int j = f & 7, lane = (f >> 3) & 63, tile = f >> 9;
    int ct = tile & 7, kt = tile >> 3;
    int k = kt * 32 + ((lane >> 4) << 3) + j;
    int n = ct * 16 + (lane & 15);
    WinF[f] = (k < 784) ? f2bf(W_in[k * 128 + n]) : (u16)0;
  } else if (idx < 155425) {                    // WegF: 6*17 tiles
    int f = idx - 103201;
    int j = f & 7, lane = (f >> 3) & 63, tile = f >> 9;
    int kt = tile / 17, ct = tile - kt * 17;
    int k = kt * 32 + ((lane >> 4) << 3) + j;
    int n = ct * 16 + (lane & 15);
    float v = 0.f;
    if (n < 256) { int e = n >> 6, h = n & 63; v = W_exp[(e * 192 + k) * 64 + h]; }
    else if (n < 260) v = W_gate[k * 4 + (n - 256)];
    WegF[f] = f2bf(v);
  } else if (idx < 163617) {                    // WctxF: 2*8 tiles
    int f = idx - 155425;
    int j = f & 7, lane = (f >> 3) & 63, tile = f >> 9;
    int ct = tile & 7, kt = tile >> 3;
    int k = kt * 32 + ((lane >> 4) << 3) + j;
    int n = ct * 16 + (lane & 15);
    WctxF[f] = f2bf(W_ctx[k * 128 + n]);
  } else if (idx < 165665) {                    // WoutF: 4 tiles (N padded 3->16)
    int f = idx - 163617;
    int j = f & 7, lane = (f >> 3) & 63, kt = f >> 9;
    int k = kt * 32 + ((lane >> 4) << 3) + j;
    int n = lane & 15;
    WoutF[f] = (n < 3) ? f2bf(W_out[k * 3 + n]) : (u16)0;
  }
}

// ------------------------------------------------------------------
// Fused forward, barrier-free: 4 waves/WG, each wave owns 32 rows
// (two 16-row A-fragments) so every B-fragment load feeds 2 MFMAs.
// Per-wave private LDS block (7680 u16 = 15360 B):
//   enh [6][32][40]   (whole block)                  phase 1 -> 2
//   cmb [2][32][40]   (aliases u16 [0,2560))         phase 2 -> 3
//   ctx [32][136]     (aliases u16 [2560,6912))      phase 3 -> 4
// Same-wave DS ops are processed in order -> aliasing is safe.
// ------------------------------------------------------------------
__global__ __launch_bounds__(256, 2)
void fused_kernel(const float* __restrict__ x,
                  const float* __restrict__ b_in, const float* __restrict__ b_gate,
                  const float* __restrict__ b_exp, const float* __restrict__ b_ctx,
                  const float* __restrict__ b_out,
                  const float* __restrict__ wm, const u16* __restrict__ WinF,
                  const u16* __restrict__ WegF, const u16* __restrict__ WctxF,
                  const u16* __restrict__ WoutF,
                  float* __restrict__ out) {
  __shared__ __align__(16) u16 smem[4 * 7680];
  const int tid = threadIdx.x;
  const int wv = tid >> 6;
  const int ln = tid & 63;
  const int cb = ln & 15;        // fragment col / A-row
  const int qr = ln >> 4;        // k-quad
  u16* enhW = smem + wv * 7680;
  u16* cmbW = enhW;
  u16* ctxW = enhW + 2560;

  const int grow = blockIdx.x * 128 + wv * 32;    // this wave's first row
  const float* xr0 = x + (size_t)(grow + cb) * 784;
  const float* xr1 = xr0 + 16 * 784;

  const f32x4 vz = {0.f, 0.f, 0.f, 0.f};

  // ---- Phase 1: projected = x @ W_in (MFMA) + exact fp32 t ----
  f32x4 acc[2][8];
  #pragma unroll
  for (int f = 0; f < 2; ++f)
    for (int i = 0; i < 8; ++i) acc[f][i] = vz;
  float tp0 = 0.f, tp1 = 0.f;

  #pragma unroll
  for (int kt = 0; kt < 25; ++kt) {
    const int k0 = kt * 32 + qr * 8;
    // Clamped address for the K-tail: garbage x values are harmless because
    // WinF rows k>=784 are zero (MFMA) and wm[784..799]==0 (t-dot uses true k0).
    const int k0c = (k0 <= 776) ? k0 : 776;
    float4 a0 = *(const float4*)(xr0 + k0c);
    float4 a1 = *(const float4*)(xr0 + k0c + 4);
    float4 b0 = *(const float4*)(xr1 + k0c);
    float4 b1 = *(const float4*)(xr1 + k0c + 4);
    const float4 m0 = *(const float4*)(wm + k0);
    const float4 m1 = *(const float4*)(wm + k0 + 4);
    tp0 += a0.x * m0.x + a0.y * m0.y + a0.z * m0.z + a0.w * m0.w
         + a1.x * m1.x + a1.y * m1.y + a1.z * m1.z + a1.w * m1.w;
    tp1 += b0.x * m0.x + b0.y * m0.y + b0.z * m0.z + b0.w * m0.w
         + b1.x * m1.x + b1.y * m1.y + b1.z * m1.z + b1.w * m1.w;
    union { short8 s; u32 u[4]; } af0, af1;
    af0.u[0] = (u32)f2bf(a0.x) | ((u32)f2bf(a0.y) << 16);
    af0.u[1] = (u32)f2bf(a0.z) | ((u32)f2bf(a0.w) << 16);
    af0.u[2] = (u32)f2bf(a1.x) | ((u32)f2bf(a1.y) << 16);
    af0.u[3] = (u32)f2bf(a1.z) | ((u32)f2bf(a1.w) << 16);
    af1.u[0] = (u32)f2bf(b0.x) | ((u32)f2bf(b0.y) << 16);
    af1.u[1] = (u32)f2bf(b0.z) | ((u32)f2bf(b0.w) << 16);
    af1.u[2] = (u32)f2bf(b1.x) | ((u32)f2bf(b1.y) << 16);
    af1.u[3] = (u32)f2bf(b1.z) | ((u32)f2bf(b1.w) << 16);
    const u16* wb = WinF + (size_t)kt * 8 * 512 + ln * 8;
    #pragma unroll
    for (int ct = 0; ct < 8; ++ct) {
      short8 Bf = *(const short8*)(wb + ct * 512);
      acc[0][ct] = __builtin_amdgcn_mfma_f32_16x16x32_bf16(af0.s, Bf, acc[0][ct], 0, 0, 0);
      acc[1][ct] = __builtin_amdgcn_mfma_f32_16x16x32_bf16(af1.s, Bf, acc[1][ct], 0, 0, 0);
    }
  }

  // t: reduce partials across the 4 k-quads of each row
  tp0 += __shfl_xor(tp0, 16); tp0 += __shfl_xor(tp0, 32);
  tp1 += __shfl_xor(tp1, 16); tp1 += __shfl_xor(tp1, 32);
  const float t0 = tp0 + wm[800];
  const float t1 = tp1 + wm[800];

  // enhanced[cols 0..127] = projected + b_in  (bf16, chunked [6][32][40])
  #pragma unroll
  for (int ct = 0; ct < 8; ++ct) {
    float bi = b_in[ct * 16 + cb];
    u16* dst = enhW + (ct >> 1) * 1280 + (ct & 1) * 16 + cb;
    #pragma unroll
    for (int f = 0; f < 2; ++f)
      #pragma unroll
      for (int i = 0; i < 4; ++i)
        dst[(f * 16 + qr * 4 + i) * 40] = f2bf(acc[f][ct][i] + bi);
  }
  // enhanced[cols 128..191] = phasor bank; lane (qr,cb) does rows cb & cb+16,
  // harmonics qr*8+1 .. qr*8+8 via rotation recurrence.
  #pragma unroll
  for (int f = 0; f < 2; ++f) {
    float phi = 7.f * (f ? t1 : t0);
    float ss, cc, sd, cd;
    sincosf(phi * (float)(qr * 8 + 1), &ss, &cc);
    sincosf(phi, &sd, &cd);
    u16* pc = enhW + 4 * 1280 + (f * 16 + cb) * 40 + qr * 8;
    u16* ps = enhW + 5 * 1280 + (f * 16 + cb) * 40 + qr * 8;
    #pragma unroll
    for (int m = 0; m < 8; ++m) {
      pc[m] = f2bf(cc);
      ps[m] = f2bf(ss);
      float nc = cc * cd - ss * sd;
      ss = ss * cd + cc * sd;
      cc = nc;
    }
  }

  // ---- Phase 2: gate + experts over enhanced (K=192) ----
  f32x4 accg[2] = {vz, vz};
  #pragma unroll
  for (int kt = 0; kt < 6; ++kt) {
    short8 Bf = *(const short8*)(WegF + ((kt * 17 + 16) * 64 + ln) * 8);
    short8 Af0 = *(const short8*)(enhW + kt * 1280 + cb * 40 + qr * 8);
    short8 Af1 = *(const short8*)(enhW + kt * 1280 + (16 + cb) * 40 + qr * 8);
    accg[0] = __builtin_amdgcn_mfma_f32_16x16x32_bf16(Af0, Bf, accg[0], 0, 0, 0);
    accg[1] = __builtin_amdgcn_mfma_f32_16x16x32_bf16(Af1, Bf, accg[1], 0, 0, 0);
  }
  // softmax over expert lanes cb=0..3, then broadcast to the owning lanes
  float ge[2][4][4];                       // [frag][expert][i]
  {
    float bg = b_gate[cb & 3];
    #pragma unroll
    for (int f = 0; f < 2; ++f)
      #pragma unroll
      for (int i = 0; i < 4; ++i) {
        float gi = accg[f][i] + bg;
        float mx = fmaxf(gi, __shfl_xor(gi, 1));
        mx = fmaxf(mx, __shfl_xor(mx, 2));
        float ev = __expf(gi - mx);
        float sv = ev + __shfl_xor(ev, 1);
        sv += __shfl_xor(sv, 2);
        float g = ev / sv;
        int base = qr * 16;
        ge[f][0][i] = __shfl(g, base + 0);
        ge[f][1][i] = __shfl(g, base + 1);
        ge[f][2][i] = __shfl(g, base + 2);
        ge[f][3][i] = __shfl(g, base + 3);
      }
  }
  // experts one at a time; each B tile feeds both A fragments
  f32x4 cmb[2][4];
  #pragma unroll
  for (int f = 0; f < 2; ++f)
    for (int i = 0; i < 4; ++i) cmb[f][i] = vz;
  #pragma unroll
  for (int e = 0; e < 4; ++e) {
    f32x4 ae[2][4];
    #pragma unroll
    for (int f = 0; f < 2; ++f)
      for (int i = 0; i < 4; ++i) ae[f][i] = vz;
    #pragma unroll
    for (int kt = 0; kt < 6; ++kt) {
      short8 Af0 = *(const short8*)(enhW + kt * 1280 + cb * 40 + qr * 8);
      short8 Af1 = *(const short8*)(enhW + kt * 1280 + (16 + cb) * 40 + qr * 8);
      #pragma unroll
      for (int c2 = 0; c2 < 4; ++c2) {
        short8 Bf = *(const short8*)(WegF + ((kt * 17 + e * 4 + c2) * 64 + ln) * 8);
        ae[0][c2] = __builtin_amdgcn_mfma_f32_16x16x32_bf16(Af0, Bf, ae[0][c2], 0, 0, 0);
        ae[1][c2] = __builtin_amdgcn_mfma_f32_16x16x32_bf16(Af1, Bf, ae[1][c2], 0, 0, 0);
      }
    }
    #pragma unroll
    for (int f = 0; f < 2; ++f)
      #pragma unroll
      for (int c2 = 0; c2 < 4; ++c2) {
        float be = b_exp[e * 64 + c2 * 16 + cb];
        #pragma unroll
        for (int i = 0; i < 4; ++i)
          cmb[f][c2][i] += ge[f][e][i] * fmaxf(ae[f][c2][i] + be, 0.f);
      }
  }
  // combined -> LDS (bf16, [2][32][40]); all enh reads precede these writes
  #pragma unroll
  for (int f = 0; f < 2; ++f)
    #pragma unroll
    for (int c2 = 0; c2 < 4; ++c2) {
      u16* dst = cmbW + (c2 >> 1) * 1280 + (c2 & 1) * 16 + cb;
      #pragma unroll
      for (int i = 0; i < 4; ++i)
        dst[(f * 16 + qr * 4 + i) * 40] = f2bf(cmb[f][c2][i]);
    }

  // ---- Phase 3: ctx = tanh(combined @ W_ctx + b_ctx), K=64 ----
  f32x4 acc3[2][8];
  #pragma unroll
  for (int f = 0; f < 2; ++f)
    for (int i = 0; i < 8; ++i) acc3[f][i] = vz;
  #pragma unroll
  for (int kt = 0; kt < 2; ++kt) {
    short8 Af0 = *(const short8*)(cmbW + kt * 1280 + cb * 40 + qr * 8);
    short8 Af1 = *(const short8*)(cmbW + kt * 1280 + (16 + cb) * 40 + qr * 8);
    #pragma unroll
    for (int ct = 0; ct < 8; ++ct) {
      short8 Bf = *(const short8*)(WctxF + ((kt * 8 + ct) * 64 + ln) * 8);
      acc3[0][ct] = __builtin_amdgcn_mfma_f32_16x16x32_bf16(Af0, Bf, acc3[0][ct], 0, 0, 0);
      acc3[1][ct] = __builtin_amdgcn_mfma_f32_16x16x32_bf16(Af1, Bf, acc3[1][ct], 0, 0, 0);
    }
  }
  #pragma unroll
  for (int ct = 0; ct < 8; ++ct) {
    float bc = b_ctx[ct * 16 + cb];
    u16* dst = ctxW + ct * 16 + cb;
    #pragma unroll
    for (int f = 0; f < 2; ++f)
      #pragma unroll
      for (int i = 0; i < 4; ++i) {
        float v = acc3[f][ct][i] + bc;
        float ex = __expf(2.f * v);          // tanh via exp; saturates correctly
        dst[(f * 16 + qr * 4 + i) * 136] = f2bf(1.f - 2.f / (ex + 1.f));
      }
  }

  // ---- Phase 4: logits = ctx @ W_out + b_out (MFMA, N padded to 16) ----
  f32x4 acc4[2] = {vz, vz};
  #pragma unroll
  for (int kt = 0; kt < 4; ++kt) {
    short8 Bf = *(const short8*)(WoutF + (kt * 64 + ln) * 8);
    short8 Af0 = *(const short8*)(ctxW + cb * 136 + kt * 32 + qr * 8);
    short8 Af1 = *(const short8*)(ctxW + (16 + cb) * 136 + kt * 32 + qr * 8);
    acc4[0] = __builtin_amdgcn_mfma_f32_16x16x32_bf16(Af0, Bf, acc4[0], 0, 0, 0);
    acc4[1] = __builtin_amdgcn_mfma_f32_16x16x32_bf16(Af1, Bf, acc4[1], 0, 0, 0);
  }
  if (cb < 3) {
    float bo = b_out[cb];
    #pragma unroll
    for (int f = 0; f < 2; ++f)
      #pragma unroll
      for (int i = 0; i < 4; ++i)
        out[(size_t)(grow + f * 16 + qr * 4 + i) * 3 + cb] = acc4[f][i] + bo;
  }
}

extern "C" void kernel_launch(void* const* d_in, const int* in_sizes, int n_in,
                              void* d_out, int out_size, void* d_ws, size_t ws_size,
                              hipStream_t stream) {
  const float* x      = (const float*)d_in[0];
  const float* W_in   = (const float*)d_in[1];
  const float* b_in   = (const float*)d_in[2];
  const float* W_gate = (const float*)d_in[3];
  const float* b_gate = (const float*)d_in[4];
  const float* W_exp  = (const float*)d_in[5];
  const float* b_exp  = (const float*)d_in[6];
  const float* W_ctx  = (const float*)d_in[7];
  const float* b_ctx  = (const float*)d_in[8];
  const float* W_out  = (const float*)d_in[9];
  const float* b_out  = (const float*)d_in[10];
  float* out = (float*)d_out;

  char* ws = (char*)d_ws;
  float* wm  = (float*)(ws + OFF_WM);
  u16* WinF  = (u16*)(ws + OFF_WINF);
  u16* WegF  = (u16*)(ws + OFF_WEGF);
  u16* WctxF = (u16*)(ws + OFF_WCTXF);
  u16* WoutF = (u16*)(ws + OFF_WOUTF);

  const int B = in_sizes[0] / 784;
  prep_kernel<<<648, 256, 0, stream>>>(W_in, b_in, W_gate, W_exp, W_ctx, W_out,
                                       wm, WinF, WegF, WctxF, WoutF);
  fused_kernel<<<B / 128, 256, 0, stream>>>(x, b_in, b_gate, b_exp, b_ctx, b_out,
                                            wm, WinF, WegF, WctxF, WoutF, out);
}